// Round 7
// baseline (2868.908 us; speedup 1.0000x reference)
//
#include <hip/hip_runtime.h>
#include <math.h>

#define SEQ   2048
#define BATCH 128
#define HID   256

typedef _Float16 f16;
typedef _Float16 f16x8 __attribute__((ext_vector_type(8)));
typedef _Float16 f16x4 __attribute__((ext_vector_type(4)));
typedef float    f32x4 __attribute__((ext_vector_type(4)));

// ROUND-7: move the matvec to the (completely idle, MfmaUtil=0.0 all rounds)
// MFMA pipe. Key trick: N=1 matvec via 16x16x32_f16 BROADCAST tiles — every
// lane's B-fragment holds the SAME v-chunk (addr depends only on lane>>4),
// so all 16 D-columns are identical copies of the matvec: the MFMA does the
// K-reduce (no DPP tree), and every lane ends holding 4 complete rows (no
// redistribution, no divergence). Precision: W and v split hi+lo fp16
// (exact remainder), all 4 cross-products accumulated in fp32 -> repr error
// ~2^-21/product, predicted absmax ~3e-4 (R5's 2.44e-4 passed).
// Fragment layouts (guide §3, m89-verified C/D): A: row=lane&15,
// k=(lane>>4)*8+e; B: col=lane&15 (ignored here), k=(lane>>4)*8+e;
// D: col=lane&15 (dup), row=(lane>>4)*4+reg.
// Structure kept from validated R6: 512 thr / 8 waves / 1 block per batch
// element; v double-buffered in LDS; ONE __syncthreads/step; fused y
// epilogue (R6 win). Wave w owns rows [32w,32w+32) as M-tiles {2w,2w+1};
// lane selects half mi_s=n>>3 for its sigmoid/stores.
__global__ __launch_bounds__(512, 2)
void rnn_scan_kernel(const float* __restrict__ x,        // (SEQ, BATCH)
                     const float* __restrict__ h0,       // (BATCH, HID)
                     const float* __restrict__ W_ih,     // (HID, 1)
                     const float* __restrict__ W_hh,     // (HID, HID)
                     const float* __restrict__ W_hh_b,   // (HID, HID)
                     const float* __restrict__ b_h,      // (HID,)
                     const int*   __restrict__ context,  // scalar
                     const float* __restrict__ Wout,     // (OUT, HID), row 0
                     const float* __restrict__ bias,     // (OUT,), [0]
                     float*       __restrict__ out_hs,   // (BATCH, SEQ, HID)
                     float*       __restrict__ out_y)    // (BATCH, SEQ)
{
    const int b    = blockIdx.x;
    const int tid  = threadIdx.x;
    const int w    = tid >> 6;       // wave 0..7
    const int lane = tid & 63;
    const int n    = lane & 15;      // MFMA col (all-dup dimension)
    const int g    = lane >> 4;      // 0..3: k-group (inputs) / row-quad (output)
    const int mi_s = n >> 3;         // which of my 2 M-tiles this lane finalizes
    const int q    = n & 7;          // 0..7 within the half

    __shared__ __align__(16) f16 Vh[2][HID];   // v = 2h-1, hi fp16, dbuf
    __shared__ __align__(16) f16 Vl[2][HID];   // v lo fp16
    __shared__ float x_lds[SEQ];

    for (int t = tid; t < SEQ; t += 512)
        x_lds[t] = x[t * BATCH + b];

    const float ctx = (float)context[0];

    // A-fragments: A[i][k] = W_eff[16m+i][32kt+k], i=n, k=8g+e.
    // hi/lo fp16 split (exact remainder). 32 f16x8 = 128 regs (AGPR-ok:
    // gfx950 MFMA reads A/B from AGPRs natively, R5 proved full-rate).
    f16x8 Ah[2][8], Al[2][8];
    #pragma unroll
    for (int mi = 0; mi < 2; ++mi) {
        const int m = 2 * w + mi;
        const float* wp = W_hh   + (size_t)(16 * m + n) * HID;
        const float* bp = W_hh_b + (size_t)(16 * m + n) * HID;
        #pragma unroll
        for (int kt = 0; kt < 8; ++kt) {
            const int c0 = 32 * kt + 8 * g;
            f16x8 hv, lv;
            #pragma unroll
            for (int e = 0; e < 8; ++e) {
                const float we = wp[c0 + e] + ctx * bp[c0 + e];
                const f16 wh = (f16)we;
                hv[e] = wh;
                lv[e] = (f16)(we - (float)wh);   // exact remainder -> ~22-bit W
            }
            Ah[mi][kt] = hv;
            Al[mi][kt] = lv;
        }
    }

    // Per-lane row constants for the half this lane finalizes.
    const int rowbase = 16 * (2 * w + mi_s) + 4 * g;
    float bh4[4], win4[4];
    #pragma unroll
    for (int r = 0; r < 4; ++r) {
        bh4[r]  = b_h[rowbase + r];
        win4[r] = W_ih[rowbase + r];
    }

    // v_{-1} from h0 into buffer 0.
    if (tid < HID) {
        const float v  = 2.f * h0[(size_t)b * HID + tid] - 1.f;
        const f16   vh = (f16)v;
        Vh[0][tid] = vh;
        Vl[0][tid] = (f16)(v - (float)vh);
    }

    float* outp = out_hs + (size_t)b * SEQ * HID;

    __syncthreads();  // V[0] + x_lds ready

    auto step = [&](int t, const f16* __restrict__ vhr, const f16* __restrict__ vlr,
                    f16* __restrict__ vhw, f16* __restrict__ vlw) {
        const float xt = x_lds[t];

        const f32x4 z = {0.f, 0.f, 0.f, 0.f};
        f32x4 acc[2][2] = {{z, z}, {z, z}};   // [mi][k-parity]: 8 chains/SIMD
        #pragma unroll
        for (int kt = 0; kt < 8; ++kt) {
            // broadcast B: every lane reads v[32kt+8g .. +8) (4 uniq addrs/wave)
            const f16x8 bh = *(const f16x8*)(vhr + 32 * kt + 8 * g);
            const f16x8 bl = *(const f16x8*)(vlr + 32 * kt + 8 * g);
            const int p = kt & 1;
            #pragma unroll
            for (int mi = 0; mi < 2; ++mi) {
                acc[mi][p] = __builtin_amdgcn_mfma_f32_16x16x32_f16(Ah[mi][kt], bh, acc[mi][p], 0, 0, 0);
                acc[mi][p] = __builtin_amdgcn_mfma_f32_16x16x32_f16(Ah[mi][kt], bl, acc[mi][p], 0, 0, 0);
                acc[mi][p] = __builtin_amdgcn_mfma_f32_16x16x32_f16(Al[mi][kt], bh, acc[mi][p], 0, 0, 0);
                acc[mi][p] = __builtin_amdgcn_mfma_f32_16x16x32_f16(Al[mi][kt], bl, acc[mi][p], 0, 0, 0);
            }
        }

        // D: lane holds rows rowbase..rowbase+3 of BOTH m-tiles; finalize mi_s.
        float h0r, h1r, h2r, h3r;
        f16x4 vhp, vlp;
        #pragma unroll
        for (int r = 0; r < 4; ++r) {
            const float s0 = acc[0][0][r] + acc[0][1][r];
            const float s1 = acc[1][0][r] + acc[1][1][r];
            const float pre = (mi_s ? s1 : s0) + bh4[r] + xt * win4[r];
            const float h = 1.f / (1.f + __expf(-pre));   // IEEE div (3e-8 path)
            if (r == 0) h0r = h; else if (r == 1) h1r = h;
            else if (r == 2) h2r = h; else h3r = h;
            const float v  = 2.f * h - 1.f;
            const f16   vh = (f16)v;
            vhp[r] = vh;
            vlp[r] = (f16)(v - (float)vh);
        }

        // LDS v-write: one lane per row-quad per half (q==0 -> n=0 & n=8).
        if (q == 0) {
            *(f16x4*)(vhw + rowbase) = vhp;   // 8B, distinct quads, bank-clean
            *(f16x4*)(vlw + rowbase) = vlp;
        }
        // global h-store: lanes q<4 each store one row (static-index select,
        // rule #20: no runtime-indexed register arrays).
        if (q < 4) {
            const float hq = (q == 0) ? h0r : (q == 1) ? h1r : (q == 2) ? h2r : h3r;
            outp[(size_t)t * HID + rowbase + q] = hq;   // 16B runs, coalesced
        }
        __syncthreads();  // v for t+1 ready; old buffer fully consumed
    };

    for (int t = 0; t < SEQ; t += 2) {
        step(t,     Vh[0], Vl[0], Vh[1], Vl[1]);
        step(t + 1, Vh[1], Vl[1], Vh[0], Vl[0]);
    }

    // ---- fused head epilogue (validated R6, free): y = hs . Wout[0] + b0.
    __threadfence();
    __syncthreads();
    {
        const int sub  = tid & 15;
        const int rsub = tid >> 4;           // 0..31
        float4 w0[4];
        #pragma unroll
        for (int u = 0; u < 4; ++u)
            w0[u] = *(const float4*)(Wout + 4 * (16 * u + sub));
        const float b0 = bias[0];
        const float* hsb = out_hs + (size_t)b * SEQ * HID;
        float* yp = out_y + (size_t)b * SEQ;

        for (int r0 = 0; r0 < SEQ; r0 += 32) {
            const int t = r0 + rsub;
            const float* rp = hsb + (size_t)t * HID;
            float s = 0.f;
            #pragma unroll
            for (int u = 0; u < 4; ++u) {
                const float4 hv = *(const float4*)(rp + 4 * (16 * u + sub));
                s += hv.x * w0[u].x + hv.y * w0[u].y +
                     hv.z * w0[u].z + hv.w * w0[u].w;
            }
            s += __shfl_xor(s, 1, 64);
            s += __shfl_xor(s, 2, 64);
            s += __shfl_xor(s, 4, 64);
            s += __shfl_xor(s, 8, 64);
            if (sub == 0) yp[t] = s + b0;
        }
    }
}

extern "C" void kernel_launch(void* const* d_in, const int* in_sizes, int n_in,
                              void* d_out, int out_size, void* d_ws, size_t ws_size,
                              hipStream_t stream) {
    const float* x      = (const float*)d_in[0];
    const float* h0     = (const float*)d_in[1];
    const float* W_ih   = (const float*)d_in[2];
    const float* W_hh   = (const float*)d_in[3];
    const float* W_hh_b = (const float*)d_in[4];
    const float* b_h    = (const float*)d_in[5];
    const float* W      = (const float*)d_in[6];
    const float* bias   = (const float*)d_in[7];
    const int*   ctx    = (const int*)d_in[8];

    float* y  = (float*)d_out;                // (BATCH*SEQ,) = y[:,:,0]
    float* hs = y + (size_t)BATCH * SEQ;      // (BATCH, SEQ, HID) = out

    rnn_scan_kernel<<<BATCH, 512, 0, stream>>>(x, h0, W_ih, W_hh, W_hh_b,
                                               b_h, ctx, W, bias, hs, y);
}

// Round 8
// 1414.656 us; speedup vs baseline: 2.0280x; 2.0280x over previous
//
#include <hip/hip_runtime.h>
#include <math.h>

#define SEQ   2048
#define BATCH 128
#define HID   256
#define NCH   16   // k-chunks
#define KCH   16   // floats per chunk
#define VST   20   // chunk stride in floats (80B): 16 chunk bases -> 8 bank
                   // quads x 2 addrs = 2-way max on b128 reads (free, m136)

// dst = src's value from lane (lane perm pattern) via DPP (VALU pipe, no LDS).
// 0xB1 = quad_perm [1,0,3,2] (xor1); 0x4E = quad_perm [2,3,0,1] (xor2);
// 0x124/0x128 = row_ror:4/8 within each 16-lane row. ror8 == xor8 within 16
// lanes; ror4 == xor4 after the ror8 fold (lanes l, l^8 are then bitwise
// duplicates). Numerics validated rounds 0-6 (absmax 2.98e-08).
template <int CTRL>
__device__ __forceinline__ float dpp_mov(float x) {
    return __int_as_float(__builtin_amdgcn_update_dpp(
        __float_as_int(x), __float_as_int(x), CTRL, 0xF, 0xF, false));
}

// FINAL (= round-6 best, 1403.5us total / 1248us scan dispatch).
// Session ledger — why this exact structure is the floor:
//  R1/R2: barrier/vmcnt/store-ack tricks: no effect (drain is not the cost).
//  R3: 2x occupancy: stall invariant (lockstep waves stall together).
//  R4: independent in-program phases: zero overlap (in-order waves cannot
//      reach past a serial tail; batch-consolidation loses CUs 1:1 since
//      grid is pinned at BATCH=128 blocks).
//  R5: weights are AGPR-resident at full rate; -10 VALU instr = no change.
//  R6: head fused as epilogue: -41us (launch overhead deleted). WIN.
//  R7: MFMA broadcast-matvec: 2.3x slower (B-fragment broadcast reads
//      serialize the LDS pipe ~1536 cyc/CU/step; N=1 tiling is structural).
// Step floor = 512 cyc/SIMD FMA issue (no fp32 MFMA; packed fp32 is not
// faster per spec) + ~260 other VALU + ~650 in-order serial chain exposed
// by barrier lockstep. All measured levers exhausted.
//
// Structure: one block (512 threads, 8 waves, 2 waves/SIMD) per batch
// element; thread (R=tid>>4, l=tid&15) owns k-chunk [16l,16l+16), rows
// 8R+((tid&7)^j) j=0..7 (128 weight fp32, AGPR-resident, full-rate);
// all-DPP reduce; threads tid / tid^8 duplicate each row bitwise-
// identically; v = 2h-1 double-buffered in LDS; ONE __syncthreads/step;
// K-loop unrolled x2 for static buffer pointers; y head fused as epilogue.
__global__ __launch_bounds__(512) __attribute__((amdgpu_waves_per_eu(2, 2)))
void rnn_scan_kernel(const float* __restrict__ x,        // (SEQ, BATCH)
                     const float* __restrict__ h0,       // (BATCH, HID)
                     const float* __restrict__ W_ih,     // (HID, 1)
                     const float* __restrict__ W_hh,     // (HID, HID)
                     const float* __restrict__ W_hh_b,   // (HID, HID)
                     const float* __restrict__ b_h,      // (HID,)
                     const int*   __restrict__ context,  // scalar
                     const float* __restrict__ Wout,     // (OUT, HID), row 0
                     const float* __restrict__ bias,     // (OUT,), [0]
                     float*       __restrict__ out_hs,   // (BATCH, SEQ, HID)
                     float*       __restrict__ out_y)    // (BATCH, SEQ)
{
    const int b   = blockIdx.x;
    const int tid = threadIdx.x;
    const int R   = tid >> 4;    // row-group: rows [8R, 8R+8)
    const int l   = tid & 15;    // k-chunk index
    const int l7  = tid & 7;
    const int row = 8 * R + l7;  // row this thread owns after the reduce

    __shared__ __align__(16) float v_lds[2][NCH * VST];
    __shared__ float x_lds[SEQ];

    for (int t = tid; t < SEQ; t += 512)
        x_lds[t] = x[t * BATCH + b];

    const float ctx = (float)context[0];

    // wreg[j][c] = W_eff[8R + (l7^j)][16l + 4c .. +3]  (XOR-ordered rows)
    float4 wreg[8][4];
    #pragma unroll
    for (int j = 0; j < 8; ++j) {
        const int rj = 8 * R + (l7 ^ j);
        const float* wp = W_hh   + (size_t)rj * HID + KCH * l;
        const float* bp = W_hh_b + (size_t)rj * HID + KCH * l;
        #pragma unroll
        for (int c = 0; c < 4; ++c) {
            const float4 a = *(const float4*)(wp + 4 * c);
            const float4 d = *(const float4*)(bp + 4 * c);
            wreg[j][c] = make_float4(a.x + ctx * d.x, a.y + ctx * d.y,
                                     a.z + ctx * d.z, a.w + ctx * d.w);
        }
    }

    const float winj = W_ih[row];
    const float bhj  = b_h[row];

    const int voff = VST * (row >> 4) + (row & 15);
    v_lds[0][voff] = 2.f * h0[(size_t)b * HID + row] - 1.f;  // dup-safe

    float* outp = out_hs + (size_t)b * SEQ * HID + row;

    const float4* vr0 = (const float4*)(v_lds[0] + VST * l);  // 80B-stride
    const float4* vr1 = (const float4*)(v_lds[1] + VST * l);

    __syncthreads();  // v[0] + x_lds ready

    auto step = [&](int t, const float4* __restrict__ vr, float* __restrict__ vw) {
        const float xt = x_lds[t];   // hoisted: issue with the v-read burst
        float q[8] = {0.f, 0.f, 0.f, 0.f, 0.f, 0.f, 0.f, 0.f};
        #pragma unroll
        for (int c = 0; c < 4; ++c) {
            const float4 v4 = vr[c];
            #pragma unroll
            for (int j = 0; j < 8; ++j) {
                const float4 w = wreg[j][c];
                q[j] += w.x * v4.x;
                q[j] += w.y * v4.y;
                q[j] += w.z * v4.z;
                q[j] += w.w * v4.w;
            }
        }
        // Fold l <-> l^8: same rows, complementary k-halves.
        #pragma unroll
        for (int j = 0; j < 8; ++j) q[j] += dpp_mov<0x128>(q[j]);
        // XOR transpose-reduce, small masks first (all DPP, no LDS).
        q[0] += dpp_mov<0xB1>(q[1]);
        q[2] += dpp_mov<0xB1>(q[3]);
        q[4] += dpp_mov<0xB1>(q[5]);
        q[6] += dpp_mov<0xB1>(q[7]);
        q[0] += dpp_mov<0x4E>(q[2]);
        q[4] += dpp_mov<0x4E>(q[6]);
        q[0] += dpp_mov<0x124>(q[4]);
        // q[0] = full dot for row 8R + l7 (dup in tid and tid^8)

        const float pre = q[0] + bhj + xt * winj;
        const float h = 1.f / (1.f + __expf(-pre));   // IEEE div: absmax 3e-8
        vw[voff] = 2.f * h - 1.f;                 // dup write, same value
        if ((tid & 8) == 0)
            outp[(size_t)t * HID] = h;            // 32 lanes/wave, 64B runs
        __syncthreads();  // v for t+1 ready; buffer t fully read before reuse
    };

    for (int t = 0; t < SEQ; t += 2) {
        step(t,     vr0, v_lds[1]);
        step(t + 1, vr1, v_lds[0]);
    }

    // ---- fused head epilogue (validated R6, free): y = hs . Wout[0] + b0.
    // Our block wrote all of hs[b]; fence + barrier make the stores visible
    // block-wide. 16 lanes/row x 16 floats/lane, 32 rows in flight,
    // shfl-xor tree over 16 lanes; hs re-read is L2-resident.
    __threadfence();
    __syncthreads();
    {
        const int sub  = tid & 15;
        const int rsub = tid >> 4;           // 0..31
        float4 w0[4];
        #pragma unroll
        for (int u = 0; u < 4; ++u)
            w0[u] = *(const float4*)(Wout + 4 * (16 * u + sub));
        const float b0 = bias[0];
        const float* hsb = out_hs + (size_t)b * SEQ * HID;
        float* yp = out_y + (size_t)b * SEQ;

        for (int r0 = 0; r0 < SEQ; r0 += 32) {
            const int t = r0 + rsub;
            const float* rp = hsb + (size_t)t * HID;
            float s = 0.f;
            #pragma unroll
            for (int u = 0; u < 4; ++u) {
                const float4 hv = *(const float4*)(rp + 4 * (16 * u + sub));
                s += hv.x * w0[u].x + hv.y * w0[u].y +
                     hv.z * w0[u].z + hv.w * w0[u].w;
            }
            s += __shfl_xor(s, 1, 64);
            s += __shfl_xor(s, 2, 64);
            s += __shfl_xor(s, 4, 64);
            s += __shfl_xor(s, 8, 64);
            if (sub == 0) yp[t] = s + b0;
        }
    }
}

extern "C" void kernel_launch(void* const* d_in, const int* in_sizes, int n_in,
                              void* d_out, int out_size, void* d_ws, size_t ws_size,
                              hipStream_t stream) {
    const float* x      = (const float*)d_in[0];
    const float* h0     = (const float*)d_in[1];
    const float* W_ih   = (const float*)d_in[2];
    const float* W_hh   = (const float*)d_in[3];
    const float* W_hh_b = (const float*)d_in[4];
    const float* b_h    = (const float*)d_in[5];
    const float* W      = (const float*)d_in[6];
    const float* bias   = (const float*)d_in[7];
    const int*   ctx    = (const int*)d_in[8];

    float* y  = (float*)d_out;                // (BATCH*SEQ,) = y[:,:,0]
    float* hs = y + (size_t)BATCH * SEQ;      // (BATCH, SEQ, HID) = out

    rnn_scan_kernel<<<BATCH, 512, 0, stream>>>(x, h0, W_ih, W_hh, W_hh_b,
                                               b_h, ctx, W, bias, hs, y);
}